// Round 8
// baseline (250.863 us; speedup 1.0000x reference)
//
#include <hip/hip_runtime.h>
#include <hip/hip_bf16.h>
#include <stdint.h>

typedef unsigned short u16;
typedef __attribute__((ext_vector_type(8))) short bf16x8;   // 8 bf16 = 4 VGPRs
typedef __attribute__((ext_vector_type(4))) short s16x4;    // 4 bf16 = 8B
typedef __attribute__((ext_vector_type(4))) float f32x4;

#define B_SZ 4
#define T_SZ 2048
#define C_SZ 1024
#define NH   16
#define HD   64
#define LOG2E 1.44269504088896340736f

__device__ __forceinline__ u16 f2bf(float f) {        // RNE
  unsigned int u = __float_as_uint(f);
  u += 0x7fffu + ((u >> 16) & 1u);
  return (u16)(u >> 16);
}
__device__ __forceinline__ u16 f2bf_hu(float f) {     // round-half-up (2 ops)
  return (u16)((__float_as_uint(f) + 0x8000u) >> 16);
}
__device__ __forceinline__ void gload_lds16(const u16* g, u16* l) {
  __builtin_amdgcn_global_load_lds((const __attribute__((address_space(1))) void*)g,
                                   (__attribute__((address_space(3))) void*)l, 16, 0, 0);
}

// fused fp32 -> bf16 cast for x / W_attn / W_proj (one launch, 8 elems/thread)
__global__ void cast3_f32_bf16(const float* __restrict__ x, const float* __restrict__ wa,
                               const float* __restrict__ wp, u16* __restrict__ xb,
                               u16* __restrict__ wab, u16* __restrict__ wpb) {
  const int n1 = 8192 * 1024 / 8, n2 = 3072 * 1024 / 8, n3 = 1024 * 1024 / 8;
  int i = blockIdx.x * blockDim.x + threadIdx.x;
  const float* in; u16* out; int idx;
  if (i < n1)            { in = x;  out = xb;  idx = i; }
  else if (i < n1 + n2)  { in = wa; out = wab; idx = i - n1; }
  else if (i < n1 + n2 + n3) { in = wp; out = wpb; idx = i - n1 - n2; }
  else return;
  const float4* p = (const float4*)in + (size_t)idx * 2;
  float4 a = p[0], b = p[1];
  bf16x8 o;
  o[0] = (short)f2bf(a.x); o[1] = (short)f2bf(a.y);
  o[2] = (short)f2bf(a.z); o[3] = (short)f2bf(a.w);
  o[4] = (short)f2bf(b.x); o[5] = (short)f2bf(b.y);
  o[6] = (short)f2bf(b.z); o[7] = (short)f2bf(b.w);
  ((bf16x8*)out)[idx] = o;
}

// ---------------------------------------------------------------------------
// 8-phase 256Mx128NxBK64 QKV GEMM (R7 structure, 768 blocks = 3 balanced
// rounds). NEW: Q section is pre-scaled by 0.125*log2(e) in the epilogue so
// the attention kernel's softmax needs no per-element scale multiply
// (S_scaled = (q*SC)·k — exact; bf16 relative precision unchanged).
// ---------------------------------------------------------------------------
__launch_bounds__(512, 2)
__global__ void gemm8_qkvB(const u16* __restrict__ A, const u16* __restrict__ Bw,
                           const float* __restrict__ bias,
                           u16* __restrict__ O0, u16* __restrict__ O1, u16* __restrict__ O2,
                           int M, int N, int K) {
  extern __shared__ u16 lds[];
  u16* As = lds;             // [2 buf][256*64] u16 (64KB)
  u16* Bs = lds + 32768;     // [2 buf][128*64] u16 (32KB)
  const int tid = threadIdx.x;
  const int lane = tid & 63, w = tid >> 6;
  const int wm = w >> 2, wn = w & 3;
  const int quad = lane >> 4, l16 = lane & 15;

  // bijective XCD swizzle (nwg = 768, %8 == 0)
  const int gx = gridDim.x;
  const int nwg = gx * gridDim.y;
  const int wg0 = blockIdx.y * gx + blockIdx.x;
  const int swz = (wg0 & 7) * (nwg >> 3) + (wg0 >> 3);
  const int n0 = (swz % gx) * 128;
  const int m0 = (swz / gx) * 256;

  const int dr8 = lane >> 3;
  const int dc8 = (lane & 7) ^ dr8;
  const u16* gAL = A + (size_t)(m0 + w * 8 + dr8) * K + dc8 * 8;
  const u16* gBL = Bw + (size_t)(n0 + w * 8 + dr8) * K + dc8 * 8;
  u16* dA = As + w * 512;
  u16* dB = Bs + w * 512;

  const int NT = K >> 6;     // 16

  auto stageA = [&](int tile) {   // 4 segs x 64 rows, 4 gloads/wave
    u16* d = dA + (tile & 1) * 16384;
    const u16* g = gAL + (size_t)tile * 64;
#pragma unroll
    for (int sg = 0; sg < 4; ++sg)
      gload_lds16(g + (size_t)(sg * 64) * K, d + sg * 4096);
  };
  auto stageB = [&](int tile) {   // 2 segs x 64 rows, 2 gloads/wave
    u16* d = dB + (tile & 1) * 8192;
    const u16* g = gBL + (size_t)tile * 64;
#pragma unroll
    for (int sg = 0; sg < 2; ++sg)
      gload_lds16(g + (size_t)(sg * 64) * K, d + sg * 4096);
  };

  f32x4 acc[8][2];
#pragma unroll
  for (int i = 0; i < 8; i++)
#pragma unroll
    for (int j = 0; j < 2; j++) acc[i][j] = (f32x4){0.f, 0.f, 0.f, 0.f};

  // prologue: A(0)+B(0) drained, B(1)'s 2 loads may fly
  stageA(0); stageB(0); stageB(1);
  asm volatile("s_waitcnt vmcnt(2)" ::: "memory");
  __builtin_amdgcn_s_barrier();

  const int sK0 = ((quad) ^ (l16 & 7)) * 8;
  const int sK1 = ((4 + quad) ^ (l16 & 7)) * 8;

  for (int tile = 0; tile < NT; ++tile) {
    const u16* Ab = As + (tile & 1) * 16384 + wm * 8192;
    const u16* Bb = Bs + (tile & 1) * 8192 + wn * 2048;
    bf16x8 bfr[2][2];
#pragma unroll
    for (int mp = 0; mp < 2; ++mp) {
      bf16x8 af[4][2];
#pragma unroll
      for (int a = 0; a < 4; ++a) {
        const int ro = ((mp * 4 + a) * 16 + l16) * 64;
        af[a][0] = *(const bf16x8*)&Ab[ro + sK0];
        af[a][1] = *(const bf16x8*)&Ab[ro + sK1];
      }
      if (mp == 0) {
#pragma unroll
        for (int nt = 0; nt < 2; ++nt) {
          const int ro = (nt * 16 + l16) * 64;
          bfr[nt][0] = *(const bf16x8*)&Bb[ro + sK0];
          bfr[nt][1] = *(const bf16x8*)&Bb[ro + sK1];
        }
        if (tile + 1 < NT) stageA(tile + 1);
        asm volatile("s_waitcnt lgkmcnt(8)");
      } else {
        if (tile + 2 < NT) stageB(tile + 2);
        asm volatile("s_waitcnt lgkmcnt(4)");
      }
      asm volatile("" ::: "memory");
      __builtin_amdgcn_s_barrier();
      asm volatile("s_waitcnt lgkmcnt(0)" ::: "memory");
      __builtin_amdgcn_sched_barrier(0);
      __builtin_amdgcn_s_setprio(1);
#pragma unroll
      for (int a = 0; a < 4; ++a)
#pragma unroll
        for (int nt = 0; nt < 2; ++nt) {
          f32x4 c = acc[mp * 4 + a][nt];
          c = __builtin_amdgcn_mfma_f32_16x16x32_bf16(af[a][0], bfr[nt][0], c, 0, 0, 0);
          c = __builtin_amdgcn_mfma_f32_16x16x32_bf16(af[a][1], bfr[nt][1], c, 0, 0, 0);
          acc[mp * 4 + a][nt] = c;
        }
      __builtin_amdgcn_s_setprio(0);
      if (mp == 1) {
        if (tile + 2 >= NT) asm volatile("s_waitcnt vmcnt(0)" ::: "memory");
        else                asm volatile("s_waitcnt vmcnt(2)" ::: "memory");
      }
      asm volatile("" ::: "memory");
      __builtin_amdgcn_s_barrier();
    }
  }

  float bv[2];
#pragma unroll
  for (int nt = 0; nt < 2; nt++) bv[nt] = bias[n0 + wn * 32 + nt * 16 + l16];

  const int ncol = n0 + wn * 32;
  const int nsec = ncol >> 10;                  // 0=Q,1=K,2=V (block-uniform)
  const int hh = (ncol >> 6) & 15;              // head
  const int dho = ncol & 63;                    // head-local offset (0 or 32)
  if (nsec < 2) {
    u16* dst = (nsec == 0 ? O0 : O1);           // [B,H,T,64]
    const float qs = (nsec == 0) ? (0.125f * LOG2E) : 1.0f;   // pre-scale Q
#pragma unroll
    for (int mt = 0; mt < 8; mt++) {
      const int row = m0 + wm * 128 + mt * 16 + quad * 4;
      const int bb = row >> 11;
      const int t = row & 2047;
#pragma unroll
      for (int nt = 0; nt < 2; nt++) {
        const int dh = dho + nt * 16 + l16;
        const size_t a = (((size_t)bb * NH + hh) * T_SZ + t) * HD + dh;
#pragma unroll
        for (int r = 0; r < 4; r++)
          dst[a + (size_t)r * HD] = f2bf((acc[mt][nt][r] + bv[nt]) * qs);
      }
    }
  } else {
    // V: wave-private transpose strip [32 n][136 t] u16 (single pass).
    u16* vth = O2;                              // [B,H,64,T]
    u16* S = lds + (size_t)w * (32 * 136);
#pragma unroll
    for (int mt = 0; mt < 8; ++mt)
#pragma unroll
      for (int nt = 0; nt < 2; ++nt) {
        s16x4 pk;
#pragma unroll
        for (int r = 0; r < 4; ++r) pk[r] = (short)f2bf(acc[mt][nt][r] + bv[nt]);
        *(s16x4*)&S[(nt * 16 + l16) * 136 + mt * 16 + quad * 4] = pk;
      }
    const int tbase = m0 + wm * 128;
    const int bb = tbase >> 11;
    const int tb = tbase & 2047;
    const size_t vrow = ((size_t)bb * NH + hh) * HD;
    const int tc = (lane & 15) * 8;
#pragma unroll
    for (int i = 0; i < 8; ++i) {
      const int nr = i * 4 + (lane >> 4);
      bf16x8 vv = *(const bf16x8*)&S[nr * 136 + tc];
      *(bf16x8*)&vth[(vrow + dho + nr) * T_SZ + tb + tc] = vv;
    }
  }
}

// ---------------------------------------------------------------------------
// 8-phase 256x128xBK64 proj GEMM, fp32 out. Grid 256 = 1 block/CU exactly.
// (Verified R6.)
// ---------------------------------------------------------------------------
__launch_bounds__(512, 2)
__global__ void gemm8_proj(const u16* __restrict__ A, const u16* __restrict__ Bw,
                           const float* __restrict__ bias, float* __restrict__ Cout,
                           int M, int N, int K) {
  extern __shared__ u16 lds[];
  u16* As = lds;             // [2 buf][256*64] u16
  u16* Bs = lds + 32768;     // [2 buf][128*64] u16
  const int tid = threadIdx.x;
  const int lane = tid & 63, w = tid >> 6;
  const int wm = w >> 2, wn = w & 3;
  const int quad = lane >> 4, l16 = lane & 15;

  // bijective XCD swizzle (nwg = 256, %8 == 0)
  const int gx = gridDim.x;
  const int nwg = gx * gridDim.y;
  const int wg0 = blockIdx.y * gx + blockIdx.x;
  const int swz = (wg0 & 7) * (nwg >> 3) + (wg0 >> 3);
  const int n0 = (swz % gx) * 128;
  const int m0 = (swz / gx) * 256;

  const int dr8 = lane >> 3;
  const int dc8 = (lane & 7) ^ dr8;
  const u16* gAL = A + (size_t)(m0 + w * 8 + dr8) * K + dc8 * 8;
  const u16* gBL = Bw + (size_t)(n0 + w * 8 + dr8) * K + dc8 * 8;
  u16* dA = As + w * 512;
  u16* dB = Bs + w * 512;

  const int NT = K >> 6;     // 16

  auto stageA = [&](int tile) {
    u16* d = dA + (tile & 1) * 16384;
    const u16* g = gAL + (size_t)tile * 64;
#pragma unroll
    for (int sg = 0; sg < 4; ++sg)
      gload_lds16(g + (size_t)(sg * 64) * K, d + sg * 4096);
  };
  auto stageB = [&](int tile) {
    u16* d = dB + (tile & 1) * 8192;
    const u16* g = gBL + (size_t)tile * 64;
#pragma unroll
    for (int sg = 0; sg < 2; ++sg)
      gload_lds16(g + (size_t)(sg * 64) * K, d + sg * 4096);
  };

  f32x4 acc[8][2];
#pragma unroll
  for (int i = 0; i < 8; i++)
#pragma unroll
    for (int j = 0; j < 2; j++) acc[i][j] = (f32x4){0.f, 0.f, 0.f, 0.f};

  stageA(0); stageB(0); stageB(1);
  asm volatile("s_waitcnt vmcnt(2)" ::: "memory");
  __builtin_amdgcn_s_barrier();

  const int sK0 = ((quad) ^ (l16 & 7)) * 8;
  const int sK1 = ((4 + quad) ^ (l16 & 7)) * 8;

  for (int tile = 0; tile < NT; ++tile) {
    const u16* Ab = As + (tile & 1) * 16384 + wm * 8192;
    const u16* Bb = Bs + (tile & 1) * 8192 + wn * 2048;
    bf16x8 bfr[2][2];
#pragma unroll
    for (int mp = 0; mp < 2; ++mp) {
      bf16x8 af[4][2];
#pragma unroll
      for (int a = 0; a < 4; ++a) {
        const int ro = ((mp * 4 + a) * 16 + l16) * 64;
        af[a][0] = *(const bf16x8*)&Ab[ro + sK0];
        af[a][1] = *(const bf16x8*)&Ab[ro + sK1];
      }
      if (mp == 0) {
#pragma unroll
        for (int nt = 0; nt < 2; ++nt) {
          const int ro = (nt * 16 + l16) * 64;
          bfr[nt][0] = *(const bf16x8*)&Bb[ro + sK0];
          bfr[nt][1] = *(const bf16x8*)&Bb[ro + sK1];
        }
        if (tile + 1 < NT) stageA(tile + 1);
        asm volatile("s_waitcnt lgkmcnt(8)");
      } else {
        if (tile + 2 < NT) stageB(tile + 2);
        asm volatile("s_waitcnt lgkmcnt(4)");
      }
      asm volatile("" ::: "memory");
      __builtin_amdgcn_s_barrier();
      asm volatile("s_waitcnt lgkmcnt(0)" ::: "memory");
      __builtin_amdgcn_sched_barrier(0);
      __builtin_amdgcn_s_setprio(1);
#pragma unroll
      for (int a = 0; a < 4; ++a)
#pragma unroll
        for (int nt = 0; nt < 2; ++nt) {
          f32x4 c = acc[mp * 4 + a][nt];
          c = __builtin_amdgcn_mfma_f32_16x16x32_bf16(af[a][0], bfr[nt][0], c, 0, 0, 0);
          c = __builtin_amdgcn_mfma_f32_16x16x32_bf16(af[a][1], bfr[nt][1], c, 0, 0, 0);
          acc[mp * 4 + a][nt] = c;
        }
      __builtin_amdgcn_s_setprio(0);
      if (mp == 1) {
        if (tile + 2 >= NT) asm volatile("s_waitcnt vmcnt(0)" ::: "memory");
        else                asm volatile("s_waitcnt vmcnt(2)" ::: "memory");
      }
      asm volatile("" ::: "memory");
      __builtin_amdgcn_s_barrier();
    }
  }

  float bv[2];
#pragma unroll
  for (int nt = 0; nt < 2; nt++) bv[nt] = bias[n0 + wn * 32 + nt * 16 + l16];
#pragma unroll
  for (int mt = 0; mt < 8; mt++) {
    const int row = m0 + wm * 128 + mt * 16 + quad * 4;
#pragma unroll
    for (int nt = 0; nt < 2; nt++) {
      const int col = n0 + wn * 32 + nt * 16 + l16;
#pragma unroll
      for (int r = 0; r < 4; r++)
        Cout[(size_t)(row + r) * N + col] = acc[mt][nt][r] + bv[nt];
    }
  }
}

// One k-block step, single q-tile. v12: SWAPPED QK^T — mfma(kf, qf) puts q on
// lanes (col=l16) and t in regs (row=quad*4+r). A/B fragment layouts are
// identical so the operand swap is free. Payoff: each lane's 4 P-values per
// nt are t-contiguous -> ONE s16x4 store (8 b64 writes/k-block vs 32 b16),
// and no s*SC multiply (Q pre-scaled in the QKV gemm epilogue). l_i is one
// scalar per m (lane-local row-sum), reduced across quads in the epilogue.
__device__ __forceinline__ void attn_step(
    int kb, int kbn, int w, int quad, int l16, int qt128, int sw0, int sw1,
    const u16* gK0, const u16* gK1, const u16* gV0, const u16* gV1,
    u16* KsF, u16* VsF, u16* PsW,
    const bf16x8 (&qf)[2][2], f32x4 (&o)[2][4], float (&l_i)[2]) {
  __syncthreads();   // drains DMA(kb); all waves done with buf[kb&1] from iter kb-2

  if (kb + 1 < kbn) {          // prefetch tile kb+1 into the other buffer
    const int nb = (kb + 1) & 1;
    const size_t ko = (size_t)(kb + 1) * 64 * HD;   // K advance: 64 rows
    const int vo = (kb + 1) * 64;                    // V advance: 64 cols
    gload_lds16(gK0 + ko, KsF + nb * 4096 + (2 * w) * 512);
    gload_lds16(gK1 + ko, KsF + nb * 4096 + (2 * w + 1) * 512);
    gload_lds16(gV0 + vo, VsF + nb * 4096 + (2 * w) * 512);
    gload_lds16(gV1 + vo, VsF + nb * 4096 + (2 * w + 1) * 512);
  }

  const u16* Kb = KsF + (kb & 1) * 4096;
  const u16* Vb = VsF + (kb & 1) * 4096;
  const int kt0 = kb * 64;

  // ---- QK^T (swapped): s[m][nt] -> q = l16, t = kt0 + nt*16 + quad*4 + r ----
  f32x4 s[2][4];
  __builtin_amdgcn_s_setprio(1);
#pragma unroll
  for (int nt = 0; nt < 4; nt++) {
    bf16x8 kf0 = *(const bf16x8*)&Kb[(nt * 16 + l16) * 64 + sw0];
    bf16x8 kf1 = *(const bf16x8*)&Kb[(nt * 16 + l16) * 64 + sw1];
#pragma unroll
    for (int m = 0; m < 2; m++) {
      f32x4 t0 = (f32x4){0.f, 0.f, 0.f, 0.f};
      t0 = __builtin_amdgcn_mfma_f32_16x16x32_bf16(kf0, qf[m][0], t0, 0, 0, 0);
      t0 = __builtin_amdgcn_mfma_f32_16x16x32_bf16(kf1, qf[m][1], t0, 0, 0, 0);
      s[m][nt] = t0;
    }
  }
  __builtin_amdgcn_s_setprio(0);

  // ---- softmax per m (no scale mul — Q pre-scaled); P -> strip [q][t] ----
  const int qml = quad * 4 - l16;          // (t - q) lane part
  bf16x8 p0a, p1a, p0b, p1b;               // named (no runtime-indexed array)
#pragma unroll
  for (int m = 0; m < 2; m++) {
    const int mrow = qt128 + w * 32 + m * 16;
    const bool diag = (kt0 + 64 > mrow);   // wave-uniform

    if (diag) {
#pragma unroll
      for (int nt = 0; nt < 4; nt++) {
        const int tt = kt0 + nt * 16 - mrow + qml;   // t - q for r=0
#pragma unroll
        for (int r = 0; r < 4; r++) {
          float v = (tt + r > 0) ? -10000.f : s[m][nt][r];
          s[m][nt][r] = exp2f(v);
        }
      }
    } else {
#pragma unroll
      for (int nt = 0; nt < 4; nt++)
#pragma unroll
        for (int r = 0; r < 4; r++)
          s[m][nt][r] = exp2f(s[m][nt][r]);
    }
    float ls = 0.f;
#pragma unroll
    for (int nt = 0; nt < 4; nt++)
      ls += (s[m][nt][0] + s[m][nt][1]) + (s[m][nt][2] + s[m][nt][3]);
    l_i[m] += ls;

    // pack 4 t-contiguous P values per nt -> one 8B store at [q=l16][t]
#pragma unroll
    for (int nt = 0; nt < 4; nt++) {
      s16x4 pk;
#pragma unroll
      for (int r = 0; r < 4; r++) pk[r] = (short)f2bf_hu(s[m][nt][r]);
      *(s16x4*)&PsW[l16 * 72 + nt * 16 + quad * 4] = pk;
    }
    if (m == 0) {
      p0a = *(const bf16x8*)&PsW[l16 * 72 + quad * 8];
      p1a = *(const bf16x8*)&PsW[l16 * 72 + 32 + quad * 8];
    } else {
      p0b = *(const bf16x8*)&PsW[l16 * 72 + quad * 8];
      p1b = *(const bf16x8*)&PsW[l16 * 72 + 32 + quad * 8];
    }
  }

  // ---- PV: nt-outer, m-inner (each V frag pair read once) ----
  __builtin_amdgcn_s_setprio(1);
#pragma unroll
  for (int nt = 0; nt < 4; nt++) {
    bf16x8 v0 = *(const bf16x8*)&Vb[(nt * 16 + l16) * 64 + sw0];
    bf16x8 v1 = *(const bf16x8*)&Vb[(nt * 16 + l16) * 64 + sw1];
    o[0][nt] = __builtin_amdgcn_mfma_f32_16x16x32_bf16(p0a, v0, o[0][nt], 0, 0, 0);
    o[0][nt] = __builtin_amdgcn_mfma_f32_16x16x32_bf16(p1a, v1, o[0][nt], 0, 0, 0);
    o[1][nt] = __builtin_amdgcn_mfma_f32_16x16x32_bf16(p0b, v0, o[1][nt], 0, 0, 0);
    o[1][nt] = __builtin_amdgcn_mfma_f32_16x16x32_bf16(p1b, v1, o[1][nt], 0, 0, 0);
  }
  __builtin_amdgcn_s_setprio(0);
}

// Flash attention v12: single q-tile per block, grid 1024, 3 blocks/CU,
// heavy-first dispatch, swapped-QK^T inner step (see attn_step).
__launch_bounds__(256, 3)
__global__ void attn_fused(const u16* __restrict__ qh, const u16* __restrict__ kh,
                           const u16* __restrict__ vth, u16* __restrict__ out) {
  __shared__ __align__(16) u16 Ks[2][64 * 64];   // [buf][t][d] swizzled
  __shared__ __align__(16) u16 Vs[2][64 * 64];   // [buf][d][t] swizzled
  __shared__ __align__(16) u16 Ps[4][16 * 72];   // per-wave P strip [q][t]
  const int qt = 15 - blockIdx.z;                // heavy-first dispatch
  const int h = blockIdx.x, b = blockIdx.y;
  const int tid = threadIdx.x;
  const int lane = tid & 63, w = tid >> 6;
  const int quad = lane >> 4, l16 = lane & 15;
  const size_t bh = (size_t)b * NH + h;
  const u16* Kbase = kh + bh * T_SZ * HD;
  const u16* Vbase = vth + bh * HD * T_SZ;
  const int qt128 = qt * 128;

  // DMA lane geometry (1KB segment = 8 rows x 128B): slot (dr, lane&7),
  // logical chunk dc = (lane&7)^dr  -> conflict-free swizzled tile.
  const int dr = lane >> 3;
  const int dc = (lane & 7) ^ dr;
  const u16* gK0 = Kbase + (size_t)(2 * w * 8 + dr) * HD + dc * 8;
  const u16* gK1 = Kbase + (size_t)((2 * w + 1) * 8 + dr) * HD + dc * 8;
  const u16* gV0 = Vbase + (size_t)(2 * w * 8 + dr) * T_SZ + dc * 8;
  const u16* gV1 = Vbase + (size_t)((2 * w + 1) * 8 + dr) * T_SZ + dc * 8;
  u16* KsF = &Ks[0][0];
  u16* VsF = &Vs[0][0];
  u16* PsW = &Ps[w][0];

  // Q fragments (B-operand now; layout identical: row=l16, k=quad*8+j)
  bf16x8 qf[2][2];
#pragma unroll
  for (int m = 0; m < 2; m++) {
    const int t = qt128 + w * 32 + m * 16 + l16;
    const u16* qrow = qh + (bh * T_SZ + t) * HD;
    qf[m][0] = *(const bf16x8*)(qrow + quad * 8);
    qf[m][1] = *(const bf16x8*)(qrow + 32 + quad * 8);
  }

  f32x4 o[2][4];
  float l_i[2];
#pragma unroll
  for (int m = 0; m < 2; m++) {
    l_i[m] = 0.f;
#pragma unroll
    for (int i = 0; i < 4; i++) o[m][i] = (f32x4){0.f, 0.f, 0.f, 0.f};
  }

  const int kbn = 2 * qt + 2;
  // swizzled in-row element offsets for K/V frag reads (lane-constant)
  const int sw0 = (quad ^ (l16 & 7)) * 8;
  const int sw1 = ((4 + quad) ^ (l16 & 7)) * 8;

  // prologue: stage tile 0 into buf 0
  gload_lds16(gK0, KsF + (2 * w) * 512);
  gload_lds16(gK1, KsF + (2 * w + 1) * 512);
  gload_lds16(gV0, VsF + (2 * w) * 512);
  gload_lds16(gV1, VsF + (2 * w + 1) * 512);

  for (int kb = 0; kb < kbn; kb++)
    attn_step(kb, kbn, w, quad, l16, qt128, sw0, sw1,
              gK0, gK1, gV0, gV1, KsF, VsF, PsW, qf, o, l_i);

  // epilogue: l_i[m] holds this lane's partial row-sum for q = mrow + l16
  // (t-slices quad*4..+3 per 16-block). Sum across quads, then broadcast to
  // the lanes holding that q-row's output (q-in-frag = quad*4 + r).
#pragma unroll
  for (int m = 0; m < 2; m++) {
    float v = l_i[m];
    v += __shfl_xor(v, 16);
    v += __shfl_xor(v, 32);       // all quads now hold full l(q = mrow+l16)
#pragma unroll
    for (int r = 0; r < 4; r++) {
      const float inv = 1.f / __shfl(v, quad * 4 + r);
      const int t = qt128 + w * 32 + m * 16 + quad * 4 + r;
      const size_t orow = ((size_t)b * T_SZ + t) * C_SZ + (size_t)h * HD;
#pragma unroll
      for (int nt = 0; nt < 4; nt++)
        out[orow + nt * 16 + l16] = f2bf(o[m][nt][r] * inv);
    }
  }
}

extern "C" void kernel_launch(void* const* d_in, const int* in_sizes, int n_in,
                              void* d_out, int out_size, void* d_ws, size_t ws_size,
                              hipStream_t stream) {
  (void)in_sizes; (void)n_in; (void)out_size; (void)ws_size;
  const float* x      = (const float*)d_in[0];   // [B,T,C]
  const float* W_attn = (const float*)d_in[1];   // [3C,C]
  const float* b_attn = (const float*)d_in[2];   // [3C]
  const float* W_proj = (const float*)d_in[3];   // [C,C]
  const float* b_proj = (const float*)d_in[4];   // [C]
  float* out = (float*)d_out;                    // [B,T,C] fp32

  char* ws = (char*)d_ws;
  u16* xb  = (u16*)ws;  ws += (size_t)8192 * 1024 * 2;   // 16 MB
  u16* Wab = (u16*)ws;  ws += (size_t)3072 * 1024 * 2;   //  6 MB
  u16* Wpb = (u16*)ws;  ws += (size_t)1024 * 1024 * 2;   //  2 MB
  u16* qhb = (u16*)ws;  ws += (size_t)8192 * 1024 * 2;   // 16 MB  [B,H,T,64] (pre-scaled)
  u16* khb = (u16*)ws;  ws += (size_t)8192 * 1024 * 2;   // 16 MB  [B,H,T,64]
  u16* vtb = (u16*)ws;  ws += (size_t)8192 * 1024 * 2;   // 16 MB  [B,H,64,T]
  u16* aob = (u16*)ws;                                   // 16 MB  [B,T,C]

  dim3 blk(256);
  // fused casts: (1M + 384K + 128K) 8-elem units = 6144 blocks
  cast3_f32_bf16<<<6144, blk, 0, stream>>>(x, W_attn, W_proj, xb, Wab, Wpb);

  // qkv = x @ W_attn^T + b_attn -> head-split qh/kh/vth (Q pre-scaled)
  gemm8_qkvB<<<dim3(3072 / 128, 8192 / 256), dim3(512), 98304, stream>>>(
      xb, Wab, b_attn, qhb, khb, vtb, 8192, 3072, 1024);
  // flash attention: 1024 single-tile blocks, heavy-first, 3 blocks/CU
  attn_fused<<<dim3(NH, B_SZ, 16), blk, 0, stream>>>(qhb, khb, vtb, aob);
  // y = att @ W_proj^T + b_proj (fp32 out, 8-phase 256x128 GEMM, 256 blocks)
  gemm8_proj<<<dim3(1024 / 128, 8192 / 256), dim3(512), 98304, stream>>>(
      aob, Wpb, b_proj, out, 8192, 1024, 1024);
}

// Round 9
// 244.522 us; speedup vs baseline: 1.0259x; 1.0259x over previous
//
#include <hip/hip_runtime.h>
#include <hip/hip_bf16.h>
#include <stdint.h>

typedef unsigned short u16;
typedef __attribute__((ext_vector_type(8))) short bf16x8;   // 8 bf16 = 4 VGPRs
typedef __attribute__((ext_vector_type(4))) short s16x4;    // 4 bf16 = 8B
typedef __attribute__((ext_vector_type(4))) float f32x4;

#define B_SZ 4
#define T_SZ 2048
#define C_SZ 1024
#define NH   16
#define HD   64
#define LOG2E 1.44269504088896340736f

__device__ __forceinline__ u16 f2bf(float f) {        // RNE
  unsigned int u = __float_as_uint(f);
  u += 0x7fffu + ((u >> 16) & 1u);
  return (u16)(u >> 16);
}
__device__ __forceinline__ u16 f2bf_hu(float f) {     // round-half-up (2 ops)
  return (u16)((__float_as_uint(f) + 0x8000u) >> 16);
}
__device__ __forceinline__ void gload_lds16(const u16* g, u16* l) {
  __builtin_amdgcn_global_load_lds((const __attribute__((address_space(1))) void*)g,
                                   (__attribute__((address_space(3))) void*)l, 16, 0, 0);
}

// fused fp32 -> bf16 cast for x / W_attn / W_proj (one launch, 8 elems/thread)
__global__ void cast3_f32_bf16(const float* __restrict__ x, const float* __restrict__ wa,
                               const float* __restrict__ wp, u16* __restrict__ xb,
                               u16* __restrict__ wab, u16* __restrict__ wpb) {
  const int n1 = 8192 * 1024 / 8, n2 = 3072 * 1024 / 8, n3 = 1024 * 1024 / 8;
  int i = blockIdx.x * blockDim.x + threadIdx.x;
  const float* in; u16* out; int idx;
  if (i < n1)            { in = x;  out = xb;  idx = i; }
  else if (i < n1 + n2)  { in = wa; out = wab; idx = i - n1; }
  else if (i < n1 + n2 + n3) { in = wp; out = wpb; idx = i - n1 - n2; }
  else return;
  const float4* p = (const float4*)in + (size_t)idx * 2;
  float4 a = p[0], b = p[1];
  bf16x8 o;
  o[0] = (short)f2bf(a.x); o[1] = (short)f2bf(a.y);
  o[2] = (short)f2bf(a.z); o[3] = (short)f2bf(a.w);
  o[4] = (short)f2bf(b.x); o[5] = (short)f2bf(b.y);
  o[6] = (short)f2bf(b.z); o[7] = (short)f2bf(b.w);
  ((bf16x8*)out)[idx] = o;
}

// ---------------------------------------------------------------------------
// 8-phase 256Mx128NxBK64 QKV GEMM (768 blocks = 3 balanced rounds of 256 CUs).
// Q section pre-scaled by 0.125*log2(e) in the epilogue (exact: folded into
// the bf16 round of q; softmax then needs no per-element scale multiply).
// ---------------------------------------------------------------------------
__launch_bounds__(512, 2)
__global__ void gemm8_qkvB(const u16* __restrict__ A, const u16* __restrict__ Bw,
                           const float* __restrict__ bias,
                           u16* __restrict__ O0, u16* __restrict__ O1, u16* __restrict__ O2,
                           int M, int N, int K) {
  extern __shared__ u16 lds[];
  u16* As = lds;             // [2 buf][256*64] u16 (64KB)
  u16* Bs = lds + 32768;     // [2 buf][128*64] u16 (32KB)
  const int tid = threadIdx.x;
  const int lane = tid & 63, w = tid >> 6;
  const int wm = w >> 2, wn = w & 3;
  const int quad = lane >> 4, l16 = lane & 15;

  // bijective XCD swizzle (nwg = 768, %8 == 0)
  const int gx = gridDim.x;
  const int nwg = gx * gridDim.y;
  const int wg0 = blockIdx.y * gx + blockIdx.x;
  const int swz = (wg0 & 7) * (nwg >> 3) + (wg0 >> 3);
  const int n0 = (swz % gx) * 128;
  const int m0 = (swz / gx) * 256;

  const int dr8 = lane >> 3;
  const int dc8 = (lane & 7) ^ dr8;
  const u16* gAL = A + (size_t)(m0 + w * 8 + dr8) * K + dc8 * 8;
  const u16* gBL = Bw + (size_t)(n0 + w * 8 + dr8) * K + dc8 * 8;
  u16* dA = As + w * 512;
  u16* dB = Bs + w * 512;

  const int NT = K >> 6;     // 16

  auto stageA = [&](int tile) {   // 4 segs x 64 rows, 4 gloads/wave
    u16* d = dA + (tile & 1) * 16384;
    const u16* g = gAL + (size_t)tile * 64;
#pragma unroll
    for (int sg = 0; sg < 4; ++sg)
      gload_lds16(g + (size_t)(sg * 64) * K, d + sg * 4096);
  };
  auto stageB = [&](int tile) {   // 2 segs x 64 rows, 2 gloads/wave
    u16* d = dB + (tile & 1) * 8192;
    const u16* g = gBL + (size_t)tile * 64;
#pragma unroll
    for (int sg = 0; sg < 2; ++sg)
      gload_lds16(g + (size_t)(sg * 64) * K, d + sg * 4096);
  };

  f32x4 acc[8][2];
#pragma unroll
  for (int i = 0; i < 8; i++)
#pragma unroll
    for (int j = 0; j < 2; j++) acc[i][j] = (f32x4){0.f, 0.f, 0.f, 0.f};

  // prologue: A(0)+B(0) drained, B(1)'s 2 loads may fly
  stageA(0); stageB(0); stageB(1);
  asm volatile("s_waitcnt vmcnt(2)" ::: "memory");
  __builtin_amdgcn_s_barrier();

  const int sK0 = ((quad) ^ (l16 & 7)) * 8;
  const int sK1 = ((4 + quad) ^ (l16 & 7)) * 8;

  for (int tile = 0; tile < NT; ++tile) {
    const u16* Ab = As + (tile & 1) * 16384 + wm * 8192;
    const u16* Bb = Bs + (tile & 1) * 8192 + wn * 2048;
    bf16x8 bfr[2][2];
#pragma unroll
    for (int mp = 0; mp < 2; ++mp) {
      bf16x8 af[4][2];
#pragma unroll
      for (int a = 0; a < 4; ++a) {
        const int ro = ((mp * 4 + a) * 16 + l16) * 64;
        af[a][0] = *(const bf16x8*)&Ab[ro + sK0];
        af[a][1] = *(const bf16x8*)&Ab[ro + sK1];
      }
      if (mp == 0) {
#pragma unroll
        for (int nt = 0; nt < 2; ++nt) {
          const int ro = (nt * 16 + l16) * 64;
          bfr[nt][0] = *(const bf16x8*)&Bb[ro + sK0];
          bfr[nt][1] = *(const bf16x8*)&Bb[ro + sK1];
        }
        if (tile + 1 < NT) stageA(tile + 1);
        asm volatile("s_waitcnt lgkmcnt(8)");
      } else {
        if (tile + 2 < NT) stageB(tile + 2);
        asm volatile("s_waitcnt lgkmcnt(4)");
      }
      asm volatile("" ::: "memory");
      __builtin_amdgcn_s_barrier();
      asm volatile("s_waitcnt lgkmcnt(0)" ::: "memory");
      __builtin_amdgcn_sched_barrier(0);
      __builtin_amdgcn_s_setprio(1);
#pragma unroll
      for (int a = 0; a < 4; ++a)
#pragma unroll
        for (int nt = 0; nt < 2; ++nt) {
          f32x4 c = acc[mp * 4 + a][nt];
          c = __builtin_amdgcn_mfma_f32_16x16x32_bf16(af[a][0], bfr[nt][0], c, 0, 0, 0);
          c = __builtin_amdgcn_mfma_f32_16x16x32_bf16(af[a][1], bfr[nt][1], c, 0, 0, 0);
          acc[mp * 4 + a][nt] = c;
        }
      __builtin_amdgcn_s_setprio(0);
      if (mp == 1) {
        if (tile + 2 >= NT) asm volatile("s_waitcnt vmcnt(0)" ::: "memory");
        else                asm volatile("s_waitcnt vmcnt(2)" ::: "memory");
      }
      asm volatile("" ::: "memory");
      __builtin_amdgcn_s_barrier();
    }
  }

  float bv[2];
#pragma unroll
  for (int nt = 0; nt < 2; nt++) bv[nt] = bias[n0 + wn * 32 + nt * 16 + l16];

  const int ncol = n0 + wn * 32;
  const int nsec = ncol >> 10;                  // 0=Q,1=K,2=V (block-uniform)
  const int hh = (ncol >> 6) & 15;              // head
  const int dho = ncol & 63;                    // head-local offset (0 or 32)
  if (nsec < 2) {
    u16* dst = (nsec == 0 ? O0 : O1);           // [B,H,T,64]
    const float qs = (nsec == 0) ? (0.125f * LOG2E) : 1.0f;   // pre-scale Q
#pragma unroll
    for (int mt = 0; mt < 8; mt++) {
      const int row = m0 + wm * 128 + mt * 16 + quad * 4;
      const int bb = row >> 11;
      const int t = row & 2047;
#pragma unroll
      for (int nt = 0; nt < 2; nt++) {
        const int dh = dho + nt * 16 + l16;
        const size_t a = (((size_t)bb * NH + hh) * T_SZ + t) * HD + dh;
#pragma unroll
        for (int r = 0; r < 4; r++)
          dst[a + (size_t)r * HD] = f2bf((acc[mt][nt][r] + bv[nt]) * qs);
      }
    }
  } else {
    // V: wave-private transpose strip [32 n][136 t] u16 (single pass).
    u16* vth = O2;                              // [B,H,64,T]
    u16* S = lds + (size_t)w * (32 * 136);
#pragma unroll
    for (int mt = 0; mt < 8; ++mt)
#pragma unroll
      for (int nt = 0; nt < 2; ++nt) {
        s16x4 pk;
#pragma unroll
        for (int r = 0; r < 4; ++r) pk[r] = (short)f2bf(acc[mt][nt][r] + bv[nt]);
        *(s16x4*)&S[(nt * 16 + l16) * 136 + mt * 16 + quad * 4] = pk;
      }
    const int tbase = m0 + wm * 128;
    const int bb = tbase >> 11;
    const int tb = tbase & 2047;
    const size_t vrow = ((size_t)bb * NH + hh) * HD;
    const int tc = (lane & 15) * 8;
#pragma unroll
    for (int i = 0; i < 8; ++i) {
      const int nr = i * 4 + (lane >> 4);
      bf16x8 vv = *(const bf16x8*)&S[nr * 136 + tc];
      *(bf16x8*)&vth[(vrow + dho + nr) * T_SZ + tb + tc] = vv;
    }
  }
}

// ---------------------------------------------------------------------------
// 8-phase 256x128xBK64 proj GEMM, fp32 out. Grid 256 = 1 block/CU exactly.
// (Verified R6.)
// ---------------------------------------------------------------------------
__launch_bounds__(512, 2)
__global__ void gemm8_proj(const u16* __restrict__ A, const u16* __restrict__ Bw,
                           const float* __restrict__ bias, float* __restrict__ Cout,
                           int M, int N, int K) {
  extern __shared__ u16 lds[];
  u16* As = lds;             // [2 buf][256*64] u16
  u16* Bs = lds + 32768;     // [2 buf][128*64] u16
  const int tid = threadIdx.x;
  const int lane = tid & 63, w = tid >> 6;
  const int wm = w >> 2, wn = w & 3;
  const int quad = lane >> 4, l16 = lane & 15;

  // bijective XCD swizzle (nwg = 256, %8 == 0)
  const int gx = gridDim.x;
  const int nwg = gx * gridDim.y;
  const int wg0 = blockIdx.y * gx + blockIdx.x;
  const int swz = (wg0 & 7) * (nwg >> 3) + (wg0 >> 3);
  const int n0 = (swz % gx) * 128;
  const int m0 = (swz / gx) * 256;

  const int dr8 = lane >> 3;
  const int dc8 = (lane & 7) ^ dr8;
  const u16* gAL = A + (size_t)(m0 + w * 8 + dr8) * K + dc8 * 8;
  const u16* gBL = Bw + (size_t)(n0 + w * 8 + dr8) * K + dc8 * 8;
  u16* dA = As + w * 512;
  u16* dB = Bs + w * 512;

  const int NT = K >> 6;     // 16

  auto stageA = [&](int tile) {
    u16* d = dA + (tile & 1) * 16384;
    const u16* g = gAL + (size_t)tile * 64;
#pragma unroll
    for (int sg = 0; sg < 4; ++sg)
      gload_lds16(g + (size_t)(sg * 64) * K, d + sg * 4096);
  };
  auto stageB = [&](int tile) {
    u16* d = dB + (tile & 1) * 8192;
    const u16* g = gBL + (size_t)tile * 64;
#pragma unroll
    for (int sg = 0; sg < 2; ++sg)
      gload_lds16(g + (size_t)(sg * 64) * K, d + sg * 4096);
  };

  f32x4 acc[8][2];
#pragma unroll
  for (int i = 0; i < 8; i++)
#pragma unroll
    for (int j = 0; j < 2; j++) acc[i][j] = (f32x4){0.f, 0.f, 0.f, 0.f};

  stageA(0); stageB(0); stageB(1);
  asm volatile("s_waitcnt vmcnt(2)" ::: "memory");
  __builtin_amdgcn_s_barrier();

  const int sK0 = ((quad) ^ (l16 & 7)) * 8;
  const int sK1 = ((4 + quad) ^ (l16 & 7)) * 8;

  for (int tile = 0; tile < NT; ++tile) {
    const u16* Ab = As + (tile & 1) * 16384 + wm * 8192;
    const u16* Bb = Bs + (tile & 1) * 8192 + wn * 2048;
    bf16x8 bfr[2][2];
#pragma unroll
    for (int mp = 0; mp < 2; ++mp) {
      bf16x8 af[4][2];
#pragma unroll
      for (int a = 0; a < 4; ++a) {
        const int ro = ((mp * 4 + a) * 16 + l16) * 64;
        af[a][0] = *(const bf16x8*)&Ab[ro + sK0];
        af[a][1] = *(const bf16x8*)&Ab[ro + sK1];
      }
      if (mp == 0) {
#pragma unroll
        for (int nt = 0; nt < 2; ++nt) {
          const int ro = (nt * 16 + l16) * 64;
          bfr[nt][0] = *(const bf16x8*)&Bb[ro + sK0];
          bfr[nt][1] = *(const bf16x8*)&Bb[ro + sK1];
        }
        if (tile + 1 < NT) stageA(tile + 1);
        asm volatile("s_waitcnt lgkmcnt(8)");
      } else {
        if (tile + 2 < NT) stageB(tile + 2);
        asm volatile("s_waitcnt lgkmcnt(4)");
      }
      asm volatile("" ::: "memory");
      __builtin_amdgcn_s_barrier();
      asm volatile("s_waitcnt lgkmcnt(0)" ::: "memory");
      __builtin_amdgcn_sched_barrier(0);
      __builtin_amdgcn_s_setprio(1);
#pragma unroll
      for (int a = 0; a < 4; ++a)
#pragma unroll
        for (int nt = 0; nt < 2; ++nt) {
          f32x4 c = acc[mp * 4 + a][nt];
          c = __builtin_amdgcn_mfma_f32_16x16x32_bf16(af[a][0], bfr[nt][0], c, 0, 0, 0);
          c = __builtin_amdgcn_mfma_f32_16x16x32_bf16(af[a][1], bfr[nt][1], c, 0, 0, 0);
          acc[mp * 4 + a][nt] = c;
        }
      __builtin_amdgcn_s_setprio(0);
      if (mp == 1) {
        if (tile + 2 >= NT) asm volatile("s_waitcnt vmcnt(0)" ::: "memory");
        else                asm volatile("s_waitcnt vmcnt(2)" ::: "memory");
      }
      asm volatile("" ::: "memory");
      __builtin_amdgcn_s_barrier();
    }
  }

  float bv[2];
#pragma unroll
  for (int nt = 0; nt < 2; nt++) bv[nt] = bias[n0 + wn * 32 + nt * 16 + l16];
#pragma unroll
  for (int mt = 0; mt < 8; mt++) {
    const int row = m0 + wm * 128 + mt * 16 + quad * 4;
#pragma unroll
    for (int nt = 0; nt < 2; nt++) {
      const int col = n0 + wn * 32 + nt * 16 + l16;
#pragma unroll
      for (int r = 0; r < 4; r++)
        Cout[(size_t)(row + r) * N + col] = acc[mt][nt][r] + bv[nt];
    }
  }
}

// One k-block step, single q-tile. v13 = R5-proven inner mechanics (nt-outer
// K/V frag reads, scalar b16 P-stores at stride 72 — R8's s16x4 layout
// TRIPLED bank conflicts, reverted) + Q pre-scaled (no s*SC multiply) +
// exact skip of fully-masked waves on the last k-block.
__device__ __forceinline__ void attn_step(
    int kb, int kbn, int w, int quad, int l16, int qt128, int sw0, int sw1,
    const u16* gK0, const u16* gK1, const u16* gV0, const u16* gV1,
    u16* KsF, u16* VsF, u16* PsW,
    const bf16x8 (&qf)[2][2], f32x4 (&o)[2][4], float (&l_i)[2][4]) {
  __syncthreads();   // drains DMA(kb); all waves done with buf[kb&1] from iter kb-2

  if (kb + 1 < kbn) {          // prefetch tile kb+1 into the other buffer
    const int nb = (kb + 1) & 1;
    const size_t ko = (size_t)(kb + 1) * 64 * HD;   // K advance: 64 rows
    const int vo = (kb + 1) * 64;                    // V advance: 64 cols
    gload_lds16(gK0 + ko, KsF + nb * 4096 + (2 * w) * 512);
    gload_lds16(gK1 + ko, KsF + nb * 4096 + (2 * w + 1) * 512);
    gload_lds16(gV0 + vo, VsF + nb * 4096 + (2 * w) * 512);
    gload_lds16(gV1 + vo, VsF + nb * 4096 + (2 * w + 1) * 512);
  }

  // last k-block: waves 0,1 have their whole 32x64 S-region above the
  // diagonal -> P == exp2(-10000) == 0 exactly; skipping is bit-exact.
  // (Barrier counts stay matched: the only barrier is at step top.)
  if (kb == kbn - 1 && w < 2) return;

  const u16* Kb = KsF + (kb & 1) * 4096;
  const u16* Vb = VsF + (kb & 1) * 4096;
  const int kt0 = kb * 64;

  // ---- QK: nt-outer, m-inner (each K frag pair read once) ----
  f32x4 s[2][4];
  __builtin_amdgcn_s_setprio(1);
#pragma unroll
  for (int nt = 0; nt < 4; nt++) {
    bf16x8 kf0 = *(const bf16x8*)&Kb[(nt * 16 + l16) * 64 + sw0];
    bf16x8 kf1 = *(const bf16x8*)&Kb[(nt * 16 + l16) * 64 + sw1];
#pragma unroll
    for (int m = 0; m < 2; m++) {
      f32x4 t0 = (f32x4){0.f, 0.f, 0.f, 0.f};
      t0 = __builtin_amdgcn_mfma_f32_16x16x32_bf16(qf[m][0], kf0, t0, 0, 0, 0);
      t0 = __builtin_amdgcn_mfma_f32_16x16x32_bf16(qf[m][1], kf1, t0, 0, 0, 0);
      s[m][nt] = t0;
    }
  }
  __builtin_amdgcn_s_setprio(0);

  // ---- softmax per m (no scale mul — Q pre-scaled); P via strip ----
  bf16x8 p0a, p1a, p0b, p1b;   // named (no runtime-indexed array)
#pragma unroll
  for (int m = 0; m < 2; m++) {
    const int mrow = qt128 + w * 32 + m * 16;
    const int qr = mrow + quad * 4;
    const bool diag = (kt0 + 64 > mrow);       // wave-uniform

    if (diag) {
#pragma unroll
      for (int nt = 0; nt < 4; nt++) {
        const int dk = kt0 + nt * 16 + l16 - qr;   // mask iff dk > r
#pragma unroll
        for (int r = 0; r < 4; r++) {
          float v = (dk > r) ? -10000.f : s[m][nt][r];
          s[m][nt][r] = exp2f(v);
        }
      }
    } else {
#pragma unroll
      for (int nt = 0; nt < 4; nt++)
#pragma unroll
        for (int r = 0; r < 4; r++)
          s[m][nt][r] = exp2f(s[m][nt][r]);
    }
#pragma unroll
    for (int r = 0; r < 4; r++)
      l_i[m][r] += (s[m][0][r] + s[m][1][r]) + (s[m][2][r] + s[m][3][r]);

    // C/D -> strip (stride 72, immediate offsets) -> A-layout reads
#pragma unroll
    for (int nt = 0; nt < 4; nt++)
#pragma unroll
      for (int r = 0; r < 4; r++)
        PsW[(quad * 4 + r) * 72 + nt * 16 + l16] = f2bf_hu(s[m][nt][r]);
    if (m == 0) {
      p0a = *(const bf16x8*)&PsW[l16 * 72 + quad * 8];
      p1a = *(const bf16x8*)&PsW[l16 * 72 + 32 + quad * 8];
    } else {
      p0b = *(const bf16x8*)&PsW[l16 * 72 + quad * 8];
      p1b = *(const bf16x8*)&PsW[l16 * 72 + 32 + quad * 8];
    }
  }

  // ---- PV: nt-outer, m-inner (each V frag pair read once) ----
  __builtin_amdgcn_s_setprio(1);
#pragma unroll
  for (int nt = 0; nt < 4; nt++) {
    bf16x8 v0 = *(const bf16x8*)&Vb[(nt * 16 + l16) * 64 + sw0];
    bf16x8 v1 = *(const bf16x8*)&Vb[(nt * 16 + l16) * 64 + sw1];
    o[0][nt] = __builtin_amdgcn_mfma_f32_16x16x32_bf16(p0a, v0, o[0][nt], 0, 0, 0);
    o[0][nt] = __builtin_amdgcn_mfma_f32_16x16x32_bf16(p1a, v1, o[0][nt], 0, 0, 0);
    o[1][nt] = __builtin_amdgcn_mfma_f32_16x16x32_bf16(p0b, v0, o[1][nt], 0, 0, 0);
    o[1][nt] = __builtin_amdgcn_mfma_f32_16x16x32_bf16(p1b, v1, o[1][nt], 0, 0, 0);
  }
  __builtin_amdgcn_s_setprio(0);
}

// Flash attention v13: single q-tile per block, grid 1024, 3 blocks/CU,
// heavy-first dispatch (qt = 15 - blockIdx.z), R5 inner step + prescaled Q
// + exact tail-wave skip.
__launch_bounds__(256, 3)
__global__ void attn_fused(const u16* __restrict__ qh, const u16* __restrict__ kh,
                           const u16* __restrict__ vth, u16* __restrict__ out) {
  __shared__ __align__(16) u16 Ks[2][64 * 64];   // [buf][t][d] swizzled
  __shared__ __align__(16) u16 Vs[2][64 * 64];   // [buf][d][t] swizzled
  __shared__ __align__(16) u16 Ps[4][16 * 72];   // per-wave P strip [q][t]
  const int qt = 15 - blockIdx.z;                // heavy-first dispatch
  const int h = blockIdx.x, b = blockIdx.y;
  const int tid = threadIdx.x;
  const int lane = tid & 63, w = tid >> 6;
  const int quad = lane >> 4, l16 = lane & 15;
  const size_t bh = (size_t)b * NH + h;
  const u16* Kbase = kh + bh * T_SZ * HD;
  const u16* Vbase = vth + bh * HD * T_SZ;
  const int qt128 = qt * 128;

  // DMA lane geometry (1KB segment = 8 rows x 128B): slot (dr, lane&7),
  // logical chunk dc = (lane&7)^dr  -> conflict-free swizzled tile.
  const int dr = lane >> 3;
  const int dc = (lane & 7) ^ dr;
  const u16* gK0 = Kbase + (size_t)(2 * w * 8 + dr) * HD + dc * 8;
  const u16* gK1 = Kbase + (size_t)((2 * w + 1) * 8 + dr) * HD + dc * 8;
  const u16* gV0 = Vbase + (size_t)(2 * w * 8 + dr) * T_SZ + dc * 8;
  const u16* gV1 = Vbase + (size_t)((2 * w + 1) * 8 + dr) * T_SZ + dc * 8;
  u16* KsF = &Ks[0][0];
  u16* VsF = &Vs[0][0];
  u16* PsW = &Ps[w][0];

  // Q fragments (A-layout: m=lane&15, k=quad*8+j); Q is pre-scaled
  bf16x8 qf[2][2];
#pragma unroll
  for (int m = 0; m < 2; m++) {
    const int t = qt128 + w * 32 + m * 16 + l16;
    const u16* qrow = qh + (bh * T_SZ + t) * HD;
    qf[m][0] = *(const bf16x8*)(qrow + quad * 8);
    qf[m][1] = *(const bf16x8*)(qrow + 32 + quad * 8);
  }

  f32x4 o[2][4];
  float l_i[2][4];
#pragma unroll
  for (int m = 0; m < 2; m++)
#pragma unroll
    for (int i = 0; i < 4; i++) {
      o[m][i] = (f32x4){0.f, 0.f, 0.f, 0.f};
      l_i[m][i] = 0.f;
    }

  const int kbn = 2 * qt + 2;
  // swizzled in-row element offsets for K/V frag reads (lane-constant)
  const int sw0 = (quad ^ (l16 & 7)) * 8;
  const int sw1 = ((4 + quad) ^ (l16 & 7)) * 8;

  // prologue: stage tile 0 into buf 0
  gload_lds16(gK0, KsF + (2 * w) * 512);
  gload_lds16(gK1, KsF + (2 * w + 1) * 512);
  gload_lds16(gV0, VsF + (2 * w) * 512);
  gload_lds16(gV1, VsF + (2 * w + 1) * 512);

  for (int kb = 0; kb < kbn; kb++)
    attn_step(kb, kbn, w, quad, l16, qt128, sw0, sw1,
              gK0, gK1, gV0, gV1, KsF, VsF, PsW, qf, o, l_i);

  // epilogue: reduce l across the 16 column-lanes, normalize, write out
#pragma unroll
  for (int m = 0; m < 2; m++)
#pragma unroll
    for (int r = 0; r < 4; r++) {
      float v = l_i[m][r];
      v += __shfl_xor(v, 1);
      v += __shfl_xor(v, 2);
      v += __shfl_xor(v, 4);
      v += __shfl_xor(v, 8);
      const float inv = 1.f / v;
      const int t = qt128 + w * 32 + m * 16 + quad * 4 + r;
      const size_t orow = ((size_t)b * T_SZ + t) * C_SZ + (size_t)h * HD;
#pragma unroll
      for (int nt = 0; nt < 4; nt++)
        out[orow + nt * 16 + l16] = f2bf(o[m][nt][r] * inv);
    }
}

extern "C" void kernel_launch(void* const* d_in, const int* in_sizes, int n_in,
                              void* d_out, int out_size, void* d_ws, size_t ws_size,
                              hipStream_t stream) {
  (void)in_sizes; (void)n_in; (void)out_size; (void)ws_size;
  const float* x      = (const float*)d_in[0];   // [B,T,C]
  const float* W_attn = (const float*)d_in[1];   // [3C,C]
  const float* b_attn = (const float*)d_in[2];   // [3C]
  const float* W_proj = (const float*)d_in[3];   // [C,C]
  const float* b_proj = (const float*)d_in[4];   // [C]
  float* out = (float*)d_out;                    // [B,T,C] fp32

  char* ws = (char*)d_ws;
  u16* xb  = (u16*)ws;  ws += (size_t)8192 * 1024 * 2;   // 16 MB
  u16* Wab = (u16*)ws;  ws += (size_t)3072 * 1024 * 2;   //  6 MB
  u16* Wpb = (u16*)ws;  ws += (size_t)1024 * 1024 * 2;   //  2 MB
  u16* qhb = (u16*)ws;  ws += (size_t)8192 * 1024 * 2;   // 16 MB  [B,H,T,64] (pre-scaled)
  u16* khb = (u16*)ws;  ws += (size_t)8192 * 1024 * 2;   // 16 MB  [B,H,T,64]
  u16* vtb = (u16*)ws;  ws += (size_t)8192 * 1024 * 2;   // 16 MB  [B,H,64,T]
  u16* aob = (u16*)ws;                                   // 16 MB  [B,T,C]

  dim3 blk(256);
  // fused casts: (1M + 384K + 128K) 8-elem units = 6144 blocks
  cast3_f32_bf16<<<6144, blk, 0, stream>>>(x, W_attn, W_proj, xb, Wab, Wpb);

  // qkv = x @ W_attn^T + b_attn -> head-split qh/kh/vth (Q pre-scaled)
  gemm8_qkvB<<<dim3(3072 / 128, 8192 / 256), dim3(512), 98304, stream>>>(
      xb, Wab, b_attn, qhb, khb, vtb, 8192, 3072, 1024);
  // flash attention: 1024 single-tile blocks, heavy-first, 3 blocks/CU
  attn_fused<<<dim3(NH, B_SZ, 16), blk, 0, stream>>>(qhb, khb, vtb, aob);
  // y = att @ W_proj^T + b_proj (fp32 out, 8-phase 256x128 GEMM, 256 blocks)
  gemm8_proj<<<dim3(1024 / 128, 8192 / 256), dim3(512), 98304, stream>>>(
      aob, Wpb, b_proj, out, 8192, 1024, 1024);
}